// Round 3
// baseline (1074.220 us; speedup 1.0000x reference)
//
#include <hip/hip_runtime.h>

// GCN 2-layer via bucket-sorted edges + LDS accumulation (no fp32 global atomics,
// no fine CSR). out = GCNConv(relu(GCNConv(x,W1,b1)), W2, b2)
// N=100k, E=1.6M, dims 64 -> 48 -> 32, fp32.

#define NN 100000
#define NE 1600000
#define NPB 128                         // nodes per bucket (dst >> 7)
#define NBUCK ((NN + NPB - 1) / NPB)    // 782
#define PBITS 17                        // bits for src (100000 < 2^17)
#define PMASK ((1 << PBITS) - 1)
#define PART_B 512
#define EPT 32                          // edges per thread in hist/part
#define PART_G ((NE + PART_B * EPT - 1) / (PART_B * EPT))   // 98

static_assert(NBUCK <= 1024, "scan assumes <=1024 buckets");
static_assert(NPB - 1 + (1 << PBITS) < (1 << 24) + (1 << PBITS), "pack fits");

__global__ void k_zero_b(int* __restrict__ bcnt) {
    int i = blockIdx.x * blockDim.x + threadIdx.x;
    if (i < NBUCK) bcnt[i] = 0;
}

// per-bucket edge histogram (LDS-staged)
__global__ void k_hist(const int* __restrict__ dst, int* __restrict__ bcnt) {
    __shared__ int h[NBUCK];
    for (int i = threadIdx.x; i < NBUCK; i += blockDim.x) h[i] = 0;
    __syncthreads();
    int base = blockIdx.x * (PART_B * EPT);
    for (int k = 0; k < EPT; ++k) {
        int e = base + k * PART_B + threadIdx.x;
        if (e < NE) atomicAdd(&h[dst[e] >> 7], 1);
    }
    __syncthreads();
    for (int i = threadIdx.x; i < NBUCK; i += blockDim.x)
        if (h[i]) atomicAdd(&bcnt[i], h[i]);
}

// single-block exclusive scan: bbase[0..NBUCK] and gcursor init
__global__ void k_scan(const int* __restrict__ bcnt, int* __restrict__ bbase,
                       int* __restrict__ gcursor) {
    __shared__ int sm[1024];
    int t = threadIdx.x;
    int v = (t < NBUCK) ? bcnt[t] : 0;
    sm[t] = v; __syncthreads();
    for (int off = 1; off < 1024; off <<= 1) {
        int xv = (t >= off) ? sm[t - off] : 0;
        __syncthreads();
        sm[t] += xv;
        __syncthreads();
    }
    if (t < NBUCK) { int ex = sm[t] - v; bbase[t] = ex; gcursor[t] = ex; }
    if (t == 0) bbase[NBUCK] = NE;
}

// partition edges into bucket order; packed word = src | (dst_local << PBITS)
__global__ void k_part(const int* __restrict__ src, const int* __restrict__ dst,
                       int* __restrict__ gcursor, int* __restrict__ sorted) {
    __shared__ int h[NBUCK];
    __shared__ int base[NBUCK];
    for (int i = threadIdx.x; i < NBUCK; i += blockDim.x) h[i] = 0;
    __syncthreads();
    int ebase = blockIdx.x * (PART_B * EPT);
    for (int k = 0; k < EPT; ++k) {
        int e = ebase + k * PART_B + threadIdx.x;
        if (e < NE) atomicAdd(&h[dst[e] >> 7], 1);
    }
    __syncthreads();
    for (int i = threadIdx.x; i < NBUCK; i += blockDim.x) {
        int c = h[i];
        if (c) base[i] = atomicAdd(&gcursor[i], c);
        h[i] = 0;
    }
    __syncthreads();
    for (int k = 0; k < EPT; ++k) {
        int e = ebase + k * PART_B + threadIdx.x;
        if (e < NE) {
            int d = dst[e];
            int b = d >> 7;
            int r = atomicAdd(&h[b], 1);
            sorted[base[b] + r] = src[e] | ((d & (NPB - 1)) << PBITS);
        }
    }
}

// per-bucket degree -> dinv (deg includes +1 self-loop)
__global__ void k_deg(const int* __restrict__ sorted, const int* __restrict__ bbase,
                      float* __restrict__ dinv) {
    __shared__ int cnt[NPB];
    int b = blockIdx.x;
    if (threadIdx.x < NPB) cnt[threadIdx.x] = 0;
    __syncthreads();
    int e0 = bbase[b], e1 = bbase[b + 1];
    for (int e = e0 + threadIdx.x; e < e1; e += blockDim.x)
        atomicAdd(&cnt[sorted[e] >> PBITS], 1);
    __syncthreads();
    int node = b * NPB + (int)threadIdx.x;
    if (threadIdx.x < NPB && node < NN)
        dinv[node] = rsqrtf((float)(cnt[threadIdx.x] + 1));
}

// Hs[M,NC] = f(X) @ W * dinv[row]; f = relu(x+bin) when RELU_IN
template <int K, int NC, bool RELU_IN>
__global__ void k_gemm(const float* __restrict__ X, const float* __restrict__ W,
                       const float* __restrict__ bin, const float* __restrict__ dinv,
                       float* __restrict__ H, int M) {
    __shared__ float w[K * NC];
    __shared__ float bb[K];
    for (int i = threadIdx.x; i < K * NC; i += blockDim.x) w[i] = W[i];
    if (RELU_IN)
        for (int i = threadIdx.x; i < K; i += blockDim.x) bb[i] = bin[i];
    __syncthreads();
    int idx = blockIdx.x * blockDim.x + threadIdx.x;
    if (idx >= M * NC) return;
    int r = idx / NC, c = idx - r * NC;
    const float* xr = X + (size_t)r * K;
    float acc = 0.f;
#pragma unroll
    for (int k = 0; k < K; ++k) {
        float v = xr[k];
        if (RELU_IN) v = fmaxf(v + bb[k], 0.f);
        acc = fmaf(v, w[k * NC + c], acc);
    }
    H[idx] = acc * dinv[r];
}

// one block per bucket: LDS-accumulate neighbor messages, then
// out[i] = dinv[i]*(Hs[i] + acc[i]) (+ b)
template <int NC, bool BIAS>
__global__ void k_agg(const float* __restrict__ Hs, const int* __restrict__ sorted,
                      const int* __restrict__ bbase, const float* __restrict__ dinv,
                      const float* __restrict__ bias, float* __restrict__ out) {
    __shared__ float acc[NPB * NC];
    for (int i = threadIdx.x; i < NPB * NC; i += blockDim.x) acc[i] = 0.f;
    __syncthreads();
    int b = blockIdx.x;
    int e0 = bbase[b], e1 = bbase[b + 1];
    int g = threadIdx.x >> 4;       // 16 groups of 16 lanes
    int l = threadIdx.x & 15;
    for (int e = e0 + g; e < e1; e += 16) {
        int v = sorted[e];
        int s = v & PMASK;
        int dl = v >> PBITS;
        const float* hr = Hs + (size_t)s * NC;
        float* ar = acc + dl * NC;
#pragma unroll
        for (int j = 0; j < NC / 16; ++j)
            atomicAdd(&ar[l + 16 * j], hr[l + 16 * j]);
    }
    __syncthreads();
    int n0 = b * NPB;
    for (int i = threadIdx.x; i < NPB * NC; i += blockDim.x) {
        int dlr = i / NC, f = i - dlr * NC;
        int node = n0 + dlr;
        if (node < NN) {
            float v = dinv[node] * (Hs[(size_t)node * NC + f] + acc[i]);
            if (BIAS) v += bias[f];
            out[(size_t)node * NC + f] = v;
        }
    }
}

extern "C" void kernel_launch(void* const* d_in, const int* in_sizes, int n_in,
                              void* d_out, int out_size, void* d_ws, size_t ws_size,
                              hipStream_t stream) {
    const float* x  = (const float*)d_in[0];
    const int*   ei = (const int*)d_in[1];   // [2,NE] int32
    const float* W1 = (const float*)d_in[2];
    const float* b1 = (const float*)d_in[3];
    const float* W2 = (const float*)d_in[4];
    const float* b2 = (const float*)d_in[5];
    float* out = (float*)d_out;

    const int* src = ei;
    const int* dst = ei + NE;

    char* p = (char*)d_ws;
    auto take = [&](size_t elems) { void* q = p; p += ((elems * 4 + 255) & ~255ull); return q; };
    int*   bcnt    = (int*)take(NBUCK);
    int*   bbase   = (int*)take(NBUCK + 1);
    int*   gcursor = (int*)take(NBUCK);
    float* dinv    = (float*)take(NN);
    int*   sorted  = (int*)take(NE);
    float* Hs      = (float*)take((size_t)NN * 48);
    float* agg1    = (float*)take((size_t)NN * 48);
    float* Hs2     = Hs;   // Hs dead after agg1

    const int B = 256;
    // --- bucket sort of edges by dst ---
    k_zero_b<<<(NBUCK + 1023) / 1024, 1024, 0, stream>>>(bcnt);
    k_hist<<<PART_G, PART_B, 0, stream>>>(dst, bcnt);
    k_scan<<<1, 1024, 0, stream>>>(bcnt, bbase, gcursor);
    k_part<<<PART_G, PART_B, 0, stream>>>(src, dst, gcursor, sorted);
    k_deg<<<NBUCK, 256, 0, stream>>>(sorted, bbase, dinv);

    // --- layer 1 ---
    k_gemm<64, 48, false><<<(NN * 48 + B - 1) / B, B, 0, stream>>>(x, W1, nullptr, dinv, Hs, NN);
    k_agg<48, false><<<NBUCK, 256, 0, stream>>>(Hs, sorted, bbase, dinv, nullptr, agg1);

    // --- layer 2 (bias1+relu fused into GEMM input read) ---
    k_gemm<48, 32, true><<<(NN * 32 + B - 1) / B, B, 0, stream>>>(agg1, W2, b1, dinv, Hs2, NN);
    k_agg<32, true><<<NBUCK, 256, 0, stream>>>(Hs2, sorted, bbase, dinv, b2, out);
}

// Round 4
// 328.698 us; speedup vs baseline: 3.2681x; 3.2681x over previous
//
#include <hip/hip_runtime.h>

// GCN 2-layer. Edges bucket-partitioned by dst (782 buckets of 128 nodes),
// then counting-sorted per bucket into a fully dst-sorted src list + row_ptr.
// Aggregation = register-accumulating gather (float4), no fp32 atomics anywhere.
// out = GCNConv(relu(GCNConv(x,W1,b1)), W2, b2); N=100k, E=1.6M, 64->48->32.

#define NN 100000
#define NE 1600000
#define NPB 128                         // nodes per bucket
#define NBUCK ((NN + NPB - 1) / NPB)    // 782
#define PBITS 17                        // src fits in 17 bits
#define PMASK ((1 << PBITS) - 1)
#define PART_B 512
#define EPT 32
#define PART_G ((NE + PART_B * EPT - 1) / (PART_B * EPT))   // 98
#define CAP 4096                        // LDS staging per bucket (mean 2048, sd ~45)

__global__ void k_zero_b(int* __restrict__ bcnt) {
    int i = threadIdx.x;
    if (i < NBUCK) bcnt[i] = 0;
}

// per-bucket edge histogram (LDS-staged, int atomics only)
__global__ void k_hist(const int* __restrict__ dst, int* __restrict__ bcnt) {
    __shared__ int h[NBUCK];
    for (int i = threadIdx.x; i < NBUCK; i += blockDim.x) h[i] = 0;
    __syncthreads();
    int base = blockIdx.x * (PART_B * EPT);
    for (int k = 0; k < EPT; ++k) {
        int e = base + k * PART_B + threadIdx.x;
        if (e < NE) atomicAdd(&h[dst[e] >> 7], 1);
    }
    __syncthreads();
    for (int i = threadIdx.x; i < NBUCK; i += blockDim.x)
        if (h[i]) atomicAdd(&bcnt[i], h[i]);
}

// single-block exclusive scan over 782 bucket counts; row_ptr[NN] = NE
__global__ void k_scan(const int* __restrict__ bcnt, int* __restrict__ bbase,
                       int* __restrict__ gcursor, int* __restrict__ row_ptr) {
    __shared__ int sm[1024];
    int t = threadIdx.x;
    int v = (t < NBUCK) ? bcnt[t] : 0;
    sm[t] = v; __syncthreads();
    for (int off = 1; off < 1024; off <<= 1) {
        int xv = (t >= off) ? sm[t - off] : 0;
        __syncthreads();
        sm[t] += xv;
        __syncthreads();
    }
    if (t < NBUCK) { int ex = sm[t] - v; bbase[t] = ex; gcursor[t] = ex; }
    if (t == 0) { bbase[NBUCK] = NE; row_ptr[NN] = NE; }
}

// partition edges into bucket order; packed = src | (dst_local << PBITS)
__global__ void k_part(const int* __restrict__ src, const int* __restrict__ dst,
                       int* __restrict__ gcursor, int* __restrict__ packed) {
    __shared__ int h[NBUCK];
    __shared__ int base[NBUCK];
    for (int i = threadIdx.x; i < NBUCK; i += blockDim.x) h[i] = 0;
    __syncthreads();
    int ebase = blockIdx.x * (PART_B * EPT);
    for (int k = 0; k < EPT; ++k) {
        int e = ebase + k * PART_B + threadIdx.x;
        if (e < NE) atomicAdd(&h[dst[e] >> 7], 1);
    }
    __syncthreads();
    for (int i = threadIdx.x; i < NBUCK; i += blockDim.x) {
        int c = h[i];
        if (c) base[i] = atomicAdd(&gcursor[i], c);
        h[i] = 0;
    }
    __syncthreads();
    for (int k = 0; k < EPT; ++k) {
        int e = ebase + k * PART_B + threadIdx.x;
        if (e < NE) {
            int d = dst[e];
            int b = d >> 7;
            int r = atomicAdd(&h[b], 1);
            packed[base[b] + r] = src[e] | ((d & (NPB - 1)) << PBITS);
        }
    }
}

// per-bucket counting sort -> fully dst-sorted src list, row_ptr, dinv.
// One 256-thread block per bucket; LDS staging; int LDS atomics only.
__global__ void k_bsort(const int* __restrict__ packed, const int* __restrict__ bbase,
                        int* __restrict__ srcsort, int* __restrict__ row_ptr,
                        float* __restrict__ dinv) {
    __shared__ int stage[CAP];
    __shared__ int cnt[NPB];
    __shared__ int pos[NPB];
    int tid = threadIdx.x, b = blockIdx.x;
    int e0 = bbase[b], e1 = bbase[b + 1], sz = e1 - e0;
    if (tid < NPB) cnt[tid] = 0;
    __syncthreads();
    for (int i = tid; i < sz; i += 256) {
        int w = packed[e0 + i];
        if (i < CAP) stage[i] = w;
        atomicAdd(&cnt[w >> PBITS], 1);
    }
    __syncthreads();
    if (tid < NPB) pos[tid] = cnt[tid];
    __syncthreads();
    for (int off = 1; off < NPB; off <<= 1) {           // inclusive scan of cnt
        int v = (tid < NPB && tid >= off) ? pos[tid - off] : 0;
        __syncthreads();
        if (tid < NPB) pos[tid] += v;
        __syncthreads();
    }
    int node = b * NPB + tid;
    if (tid < NPB) {
        int ex = pos[tid] - cnt[tid];                   // exclusive
        if (node < NN) {
            row_ptr[node] = e0 + ex;
            dinv[node] = rsqrtf((float)(cnt[tid] + 1)); // +1 self-loop
        }
        cnt[tid] = ex;                                  // reuse as cursor
    }
    __syncthreads();
    for (int i = tid; i < sz; i += 256) {
        int w = (i < CAP) ? stage[i] : packed[e0 + i];
        int dl = w >> PBITS;
        int p = atomicAdd(&cnt[dl], 1);
        srcsort[e0 + p] = w & PMASK;
    }
}

// Hs[M,NC] = f(X) @ W * dinv[row]; f = relu(x+bin) when RELU_IN. float4 X reads.
template <int K, int NC, bool RELU_IN>
__global__ void k_gemm(const float* __restrict__ X, const float* __restrict__ W,
                       const float* __restrict__ bin, const float* __restrict__ dinv,
                       float* __restrict__ H, int M) {
    __shared__ float w[K * NC];
    __shared__ float bb[K];
    for (int i = threadIdx.x; i < K * NC; i += blockDim.x) w[i] = W[i];
    if (RELU_IN)
        for (int i = threadIdx.x; i < K; i += blockDim.x) bb[i] = bin[i];
    __syncthreads();
    int idx = blockIdx.x * blockDim.x + threadIdx.x;
    if (idx >= M * NC) return;
    int r = idx / NC, c = idx - r * NC;
    const float4* xr4 = (const float4*)(X + (size_t)r * K);
    float acc = 0.f;
#pragma unroll
    for (int k4 = 0; k4 < K / 4; ++k4) {
        float4 xv = xr4[k4];
        float vs[4] = {xv.x, xv.y, xv.z, xv.w};
#pragma unroll
        for (int j = 0; j < 4; ++j) {
            float v = vs[j];
            if (RELU_IN) v = fmaxf(v + bb[4 * k4 + j], 0.f);
            acc = fmaf(v, w[(4 * k4 + j) * NC + c], acc);
        }
    }
    H[idx] = acc * dinv[r];
}

// out[i,:] = dinv[i] * (Hs[i,:] + sum_{e in row i} Hs[src_e,:]) (+ b)
// thread = (node, 4-feature chunk); float4 gathers; register accumulation.
template <int NC, bool BIAS>
__global__ void k_agg(const float* __restrict__ Hs, const int* __restrict__ row_ptr,
                      const int* __restrict__ srcsort, const float* __restrict__ dinv,
                      const float* __restrict__ bias, float* __restrict__ out) {
    constexpr int Q = NC / 4;
    int idx = blockIdx.x * blockDim.x + threadIdx.x;
    if (idx >= NN * Q) return;
    int r = idx / Q, q = idx - r * Q;
    const float4* H4 = (const float4*)Hs;
    float4 a = H4[(size_t)r * Q + q];                   // self-loop term
    float ax = a.x, ay = a.y, az = a.z, aw = a.w;
    int e0 = row_ptr[r], e1 = row_ptr[r + 1];
    for (int e = e0; e < e1; ++e) {
        int s = srcsort[e];
        float4 v = H4[(size_t)s * Q + q];
        ax += v.x; ay += v.y; az += v.z; aw += v.w;
    }
    float d = dinv[r];
    ax *= d; ay *= d; az *= d; aw *= d;
    if (BIAS) {
        const float4* b4 = (const float4*)bias;
        float4 bv = b4[q];
        ax += bv.x; ay += bv.y; az += bv.z; aw += bv.w;
    }
    float4 o = {ax, ay, az, aw};
    ((float4*)out)[(size_t)r * Q + q] = o;
}

extern "C" void kernel_launch(void* const* d_in, const int* in_sizes, int n_in,
                              void* d_out, int out_size, void* d_ws, size_t ws_size,
                              hipStream_t stream) {
    const float* x  = (const float*)d_in[0];
    const int*   ei = (const int*)d_in[1];   // [2,NE] int32
    const float* W1 = (const float*)d_in[2];
    const float* b1 = (const float*)d_in[3];
    const float* W2 = (const float*)d_in[4];
    const float* b2 = (const float*)d_in[5];
    float* out = (float*)d_out;

    const int* src = ei;
    const int* dst = ei + NE;

    char* p = (char*)d_ws;
    auto take = [&](size_t elems) { void* q = p; p += ((elems * 4 + 255) & ~255ull); return q; };
    int*   bcnt    = (int*)take(NBUCK);
    int*   bbase   = (int*)take(NBUCK + 1);
    int*   gcursor = (int*)take(NBUCK);
    int*   row_ptr = (int*)take(NN + 1);
    float* dinv    = (float*)take(NN);
    int*   srcsort = (int*)take(NE);
    float* Hs      = (float*)take((size_t)NN * 48);
    float* agg1    = (float*)take((size_t)NN * 48);
    int*   packed  = (int*)agg1;   // alias: packed dead before agg1 is written
    float* Hs2     = Hs;           // Hs dead after agg1

    const int B = 256;
    // --- dst-sort of edges ---
    k_zero_b<<<1, 1024, 0, stream>>>(bcnt);
    k_hist<<<PART_G, PART_B, 0, stream>>>(dst, bcnt);
    k_scan<<<1, 1024, 0, stream>>>(bcnt, bbase, gcursor, row_ptr);
    k_part<<<PART_G, PART_B, 0, stream>>>(src, dst, gcursor, packed);
    k_bsort<<<NBUCK, 256, 0, stream>>>(packed, bbase, srcsort, row_ptr, dinv);

    // --- layer 1 ---
    k_gemm<64, 48, false><<<(NN * 48 + B - 1) / B, B, 0, stream>>>(x, W1, nullptr, dinv, Hs, NN);
    k_agg<48, false><<<(NN * 12 + B - 1) / B, B, 0, stream>>>(Hs, row_ptr, srcsort, dinv, nullptr, agg1);

    // --- layer 2 (bias1+relu fused into GEMM input read) ---
    k_gemm<48, 32, true><<<(NN * 32 + B - 1) / B, B, 0, stream>>>(agg1, W2, b1, dinv, Hs2, NN);
    k_agg<32, true><<<(NN * 8 + B - 1) / B, B, 0, stream>>>(Hs2, row_ptr, srcsort, dinv, b2, out);
}